// Round 7
// baseline (280.559 us; speedup 1.0000x reference)
//
#include <hip/hip_runtime.h>
#include <math.h>

// LSTM: N=32768 seqs, T=600, H=5, input dim 1.
// 2 lanes/seq. R7 = R6 + asm-pinned weights:
//  R6 evidence: VGPR_Count=68 < 70-float weight footprint => compiler was
//  REMATERIALIZING pre-scaled weights per step (reload + re-multiply ~140
//  VALU cyc/step). asm volatile("" : "+v"(w)) makes each scaled weight
//  opaque -> must stay register-resident (512-VGPR budget at 1 wave/SIMD).
// Even lane (half=0): lo = i rows, hi = g rows (tanh, c~-space output).
// Odd  lane (half=1): lo = f rows, hi = o rows (sigmoid).
// Block = 64 = 1 wave = 32 seqs; grid = 1024 -> 1 wave/SIMD chip-wide.

#define LOG2E 1.44269504088896340736f

typedef float v2f __attribute__((ext_vector_type(2)));

constexpr int T_ = 600;
constexpr int SEQ_PER_BLOCK = 32;
constexpr int TTILE = 64;
constexpr int LDS_STRIDE = 68;   // 68%32=4 -> 2-way bank aliasing only (free)

__device__ __forceinline__ float fast_rcp(float v)  { return __builtin_amdgcn_rcpf(v); }
__device__ __forceinline__ float fast_exp2(float v) { return __builtin_amdgcn_exp2f(v); }

// packed fp32 fma on VGPR pairs
__device__ __forceinline__ v2f pk_fma(v2f a, v2f b, v2f c) {
    v2f d;
    asm("v_pk_fma_f32 %0, %1, %2, %3" : "=v"(d) : "v"(a), "v"(b), "v"(c));
    return d;
}

// broadcast even lane of each pair to both lanes: quad_perm [0,0,2,2] = 0xA0
// broadcast odd  lane of each pair to both lanes: quad_perm [1,1,3,3] = 0xF5
template <int CTRL>
__device__ __forceinline__ float dpp_q(float v) {
    const int x = __float_as_int(v);
    return __int_as_float(__builtin_amdgcn_update_dpp(x, x, CTRL, 0xF, 0xF, false));
}

__global__ __launch_bounds__(64, 1)
__attribute__((amdgpu_waves_per_eu(1, 1)))
void lstm_kernel(
    const float* __restrict__ x,
    const float* __restrict__ w_ih,   // (20,1)
    const float* __restrict__ w_hh,   // (20,5)
    const float* __restrict__ b_ih,   // (20,)
    const float* __restrict__ b_hh,   // (20,)
    const float* __restrict__ fc_w,   // (15,5)
    const float* __restrict__ fc_b,   // (15,)
    const float* __restrict__ out_w,  // (1,15)
    const float* __restrict__ out_b,  // (1,)
    float* __restrict__ out)          // (N,1)
{
    __shared__ float xs[SEQ_PER_BLOCK * LDS_STRIDE];

    const int lane = threadIdx.x;     // 0..63
    const int s    = lane >> 1;       // local sequence 0..31
    const int half = lane & 1;        // 0: i/g rows, 1: f/o rows
    const int seq  = blockIdx.x * SEQ_PER_BLOCK + s;

    // ---- pre-scaled per-lane weights, rows paired {lo, hi} ----
    const float slo = -LOG2E;                          // i / f: sigmoid
    const float shi = half ? -LOG2E : -2.0f * LOG2E;   // o: sigmoid, g: tanh (sig(2x))
    v2f wih2[5], bb2[5], whh2[5][5];
#pragma unroll
    for (int p = 0; p < 5; ++p) {
        const int rlo = half * 5 + p;       // i (h0) / f (h1)
        const int rhi = 10 + half * 5 + p;  // g (h0) / o (h1)
        wih2[p] = (v2f){ w_ih[rlo] * slo, w_ih[rhi] * shi };
        bb2[p]  = (v2f){ (b_ih[rlo] + b_hh[rlo]) * slo,
                         (b_ih[rhi] + b_hh[rhi]) * shi };
#pragma unroll
        for (int k = 0; k < 5; ++k)
            whh2[p][k] = (v2f){ w_hh[rlo * 5 + k] * slo, w_hh[rhi * 5 + k] * shi };
    }
    // PIN: make scaled weights opaque -> no rematerialization, stay in VGPRs
#pragma unroll
    for (int p = 0; p < 5; ++p) {
        asm volatile("" : "+v"(wih2[p]));
        asm volatile("" : "+v"(bb2[p]));
#pragma unroll
        for (int k = 0; k < 5; ++k) asm volatile("" : "+v"(whh2[p][k]));
    }

    // hi-row output transform: h0 (g): acth = -2log2e*tanh(g) (c~-space)
    //                          h1 (o): acth = sigmoid (A=1,B=0)
    const float Ahi = half ? 1.0f : (-4.0f * LOG2E);
    const float Bhi = half ? 0.0f : ( 2.0f * LOG2E);

    float h[5] = {0.f, 0.f, 0.f, 0.f, 0.f};
    float c[5] = {0.f, 0.f, 0.f, 0.f, 0.f};   // c~ = -2log2e * c_true

    const float* xblk = x + (size_t)(blockIdx.x * SEQ_PER_BLOCK) * T_;

    auto step = [&](float xt) {
        // ---- gate pre-activations (pre-scaled space): 30 v_pk_fma_f32 ----
        const v2f x2 = (v2f){ xt, xt };
        v2f g2[5];
#pragma unroll
        for (int p = 0; p < 5; ++p) g2[p] = pk_fma(x2, wih2[p], bb2[p]);
#pragma unroll
        for (int k = 0; k < 5; ++k) {
            const v2f h2 = (v2f){ h[k], h[k] };
#pragma unroll
            for (int p = 0; p < 5; ++p) g2[p] = pk_fma(h2, whh2[p][k], g2[p]);
        }
        // ---- activations, paired rcp within each {lo,hi} pair ----
        float actl[5], acth[5];
#pragma unroll
        for (int p = 0; p < 5; ++p) {
            const float dl = 1.0f + fast_exp2(g2[p].x);
            const float dh = 1.0f + fast_exp2(g2[p].y);
            const float rp = fast_rcp(dl * dh);
            actl[p] = rp * dh;                   // sigmoid: i (h0) / f (h1)
            acth[p] = fmaf(rp * dl, Ahi, Bhi);   // g~ = -2L*tanh(g) (h0) / sigmoid o (h1)
        }
        // ---- canonical values on both lanes via pair-broadcast DPP ----
        float d[5], oB[5];
#pragma unroll
        for (int k = 0; k < 5; ++k) {
            const float P  = actl[k] * acth[k];     // i*g~ on even lane
            const float PB = dpp_q<0xA0>(P);        // i*g~ on both
            const float fB = dpp_q<0xF5>(actl[k]);  // f on both
            oB[k]          = dpp_q<0xF5>(acth[k]);  // o on both
            c[k] = fmaf(fB, c[k], PB);
            d[k] = 1.0f + fast_exp2(c[k]);          // c~-space: = 1 + e^{-2c}
        }
        // tanh(c_true) = 2*rcp(d)-1, rcps paired (0,1),(2,3),(4)
        {
            const float i01 = fast_rcp(d[0] * d[1]);
            const float i23 = fast_rcp(d[2] * d[3]);
            const float i4  = fast_rcp(d[4]);
            const float r0 = i01 * d[1], r1 = i01 * d[0];
            const float r2 = i23 * d[3], r3 = i23 * d[2];
            h[0] = oB[0] * fmaf(r0, 2.0f, -1.0f);
            h[1] = oB[1] * fmaf(r1, 2.0f, -1.0f);
            h[2] = oB[2] * fmaf(r2, 2.0f, -1.0f);
            h[3] = oB[3] * fmaf(r3, 2.0f, -1.0f);
            h[4] = oB[4] * fmaf(i4, 2.0f, -1.0f);
        }
    };

    const int rrow = lane >> 4;         // 0..3
    const int ccol = (lane & 15) << 2;  // 0,4,...,60

    for (int t0 = 0; t0 < T_; t0 += TTILE) {
        __syncthreads();
        // stage 32 rows x up-to-64 cols, coalesced float4 loads
#pragma unroll
        for (int it = 0; it < 8; ++it) {
            const int r = it * 4 + rrow;
            if (t0 + ccol < T_) {
                const float4 v = *(const float4*)(xblk + (size_t)r * T_ + (t0 + ccol));
                *(float4*)&xs[r * LDS_STRIDE + ccol] = v;
            }
        }
        __syncthreads();

        const int steps = min(TTILE, T_ - t0); // 64 or 24
        const float* xr = &xs[s * LDS_STRIDE];
        for (int tt = 0; tt < steps; tt += 4) {
            const float4 xv4 = *(const float4*)&xr[tt];
            step(xv4.x);
            step(xv4.y);
            step(xv4.z);
            step(xv4.w);
        }
    }

    // ---- head: hid = h@fc_w.T + fc_b ; out = sigmoid(hid@out_w.T + out_b) ----
    if (half == 0) {
        float acc = out_b[0];
#pragma unroll
        for (int j = 0; j < 15; ++j) {
            float hid = fc_b[j];
#pragma unroll
            for (int k = 0; k < 5; ++k) hid = fmaf(h[k], fc_w[j * 5 + k], hid);
            acc = fmaf(hid, out_w[j], acc);
        }
        out[seq] = fast_rcp(1.0f + fast_exp2(-acc * LOG2E));
    }
}

extern "C" void kernel_launch(void* const* d_in, const int* in_sizes, int n_in,
                              void* d_out, int out_size, void* d_ws, size_t ws_size,
                              hipStream_t stream) {
    const float* x    = (const float*)d_in[0];
    const float* w_ih = (const float*)d_in[1];
    const float* w_hh = (const float*)d_in[2];
    const float* b_ih = (const float*)d_in[3];
    const float* b_hh = (const float*)d_in[4];
    const float* fc_w = (const float*)d_in[5];
    const float* fc_b = (const float*)d_in[6];
    const float* out_w = (const float*)d_in[7];
    const float* out_b = (const float*)d_in[8];
    float* out = (float*)d_out;

    const int N = in_sizes[0] / T_;             // 32768
    const int grid = N / SEQ_PER_BLOCK;         // 1024 blocks -> 1 wave/SIMD
    hipLaunchKernelGGL(lstm_kernel, dim3(grid), dim3(64), 0, stream,
                       x, w_ih, w_hh, b_ih, b_hh, fc_w, fc_b, out_w, out_b, out);
}

// Round 8
// 271.811 us; speedup vs baseline: 1.0322x; 1.0322x over previous
//
#include <hip/hip_runtime.h>
#include <math.h>

// LSTM: N=32768 seqs, T=600, H=5, input dim 1.
// 2 lanes/seq. R8 = R6 structure, native v2f (no asm pk_fma, no pin), plus
// SPLIT c/tanh update across the lane pair:
//   slot j=0,1,2: even lane owns c0,c1,c2; odd lane owns c3,c4 (j=2 dups c2).
//   Operand routing via pair-broadcast DPP (0xA0 even->both, 0xF5 odd->both)
//   + 6 cndmasks; h redistributed to uniform regs with 5 broadcasts.
//   Update phase: 46->40 full-rate instr, 8->5 trans  (~ -36 cyc/step).
// Even lane (half=0): lo = i rows, hi = g rows (tanh, c~-space output).
// Odd  lane (half=1): lo = f rows, hi = o rows (sigmoid).
// Block = 64 = 1 wave = 32 seqs; grid = 1024 -> 1 wave/SIMD chip-wide.

#define LOG2E 1.44269504088896340736f

typedef float v2f __attribute__((ext_vector_type(2)));

constexpr int T_ = 600;
constexpr int SEQ_PER_BLOCK = 32;
constexpr int TTILE = 64;
constexpr int LDS_STRIDE = 68;   // 68%32=4 -> 2-way bank aliasing only (free)

__device__ __forceinline__ float fast_rcp(float v)  { return __builtin_amdgcn_rcpf(v); }
__device__ __forceinline__ float fast_exp2(float v) { return __builtin_amdgcn_exp2f(v); }

// quad_perm DPP: 0xA0 = [0,0,2,2] (even lane of pair -> both),
//                0xF5 = [1,1,3,3] (odd lane of pair -> both)
template <int CTRL>
__device__ __forceinline__ float dpp_q(float v) {
    const int x = __float_as_int(v);
    return __int_as_float(__builtin_amdgcn_update_dpp(x, x, CTRL, 0xF, 0xF, false));
}

__global__ __launch_bounds__(64, 1) void lstm_kernel(
    const float* __restrict__ x,
    const float* __restrict__ w_ih,   // (20,1)
    const float* __restrict__ w_hh,   // (20,5)
    const float* __restrict__ b_ih,   // (20,)
    const float* __restrict__ b_hh,   // (20,)
    const float* __restrict__ fc_w,   // (15,5)
    const float* __restrict__ fc_b,   // (15,)
    const float* __restrict__ out_w,  // (1,15)
    const float* __restrict__ out_b,  // (1,)
    float* __restrict__ out)          // (N,1)
{
    __shared__ float xs[SEQ_PER_BLOCK * LDS_STRIDE];

    const int lane = threadIdx.x;     // 0..63
    const int s    = lane >> 1;       // local sequence 0..31
    const int half = lane & 1;        // 0: i/g rows, 1: f/o rows
    const int seq  = blockIdx.x * SEQ_PER_BLOCK + s;

    // ---- pre-scaled per-lane weights, rows paired {lo, hi} ----
    const float slo = -LOG2E;                          // i / f: sigmoid
    const float shi = half ? -LOG2E : -2.0f * LOG2E;   // o: sigmoid, g: tanh (sig(2x))
    v2f wih2[5], bb2[5], whh2[5][5];
#pragma unroll
    for (int p = 0; p < 5; ++p) {
        const int rlo = half * 5 + p;       // i (h0) / f (h1)
        const int rhi = 10 + half * 5 + p;  // g (h0) / o (h1)
        wih2[p] = (v2f){ w_ih[rlo] * slo, w_ih[rhi] * shi };
        bb2[p]  = (v2f){ (b_ih[rlo] + b_hh[rlo]) * slo,
                         (b_ih[rhi] + b_hh[rhi]) * shi };
#pragma unroll
        for (int k = 0; k < 5; ++k)
            whh2[p][k] = (v2f){ w_hh[rlo * 5 + k] * slo, w_hh[rhi * 5 + k] * shi };
    }
    // hi-row output transform: h0 (g): acth = -2log2e*tanh(g) (c~-space)
    //                          h1 (o): acth = sigmoid (A=1,B=0)
    const float Ahi = half ? 1.0f : (-4.0f * LOG2E);
    const float Bhi = half ? 0.0f : ( 2.0f * LOG2E);

    float H[5]  = {0.f, 0.f, 0.f, 0.f, 0.f};  // true h, uniform content on both lanes
    float cS[3] = {0.f, 0.f, 0.f};            // c~ slots: even (c0,c1,c2), odd (c3,c4,c2)

    const float* xblk = x + (size_t)(blockIdx.x * SEQ_PER_BLOCK) * T_;

    auto step = [&](float xt) {
        // ---- gate pre-activations (pre-scaled space), native v2f ----
        const v2f x2 = (v2f){ xt, xt };
        v2f g2[5];
#pragma unroll
        for (int p = 0; p < 5; ++p) g2[p] = x2 * wih2[p] + bb2[p];
#pragma unroll
        for (int k = 0; k < 5; ++k) {
            const v2f h2 = (v2f){ H[k], H[k] };
#pragma unroll
            for (int p = 0; p < 5; ++p) g2[p] += h2 * whh2[p][k];
        }
        // ---- activations, paired rcp within each {lo,hi} pair ----
        float actl[5], acth[5];
#pragma unroll
        for (int p = 0; p < 5; ++p) {
            const float dl = 1.0f + fast_exp2(g2[p].x);
            const float dh = 1.0f + fast_exp2(g2[p].y);
            const float rp = fast_rcp(dl * dh);
            actl[p] = rp * dh;                   // sigmoid: i (h0) / f (h1)
            acth[p] = fmaf(rp * dl, Ahi, Bhi);   // g~ = -2L*tanh(g) (h0) / sigmoid o (h1)
        }
        // ---- split update: slot j: even k=j, odd k=3+j (j=2 duplicates k=2) ----
        // P = i*g~ (valid on even lane)
        float P[5];
#pragma unroll
        for (int k = 0; k < 5; ++k) P[k] = actl[k] * acth[k];
        const float P3b = dpp_q<0xA0>(P[3]);      // i3*g~3 -> both
        const float P4b = dpp_q<0xA0>(P[4]);
        const float P2b = dpp_q<0xA0>(P[2]);      // uniform slot2
        const float f0b = dpp_q<0xF5>(actl[0]);   // f0 -> both
        const float f1b = dpp_q<0xF5>(actl[1]);
        const float f2b = dpp_q<0xF5>(actl[2]);   // uniform slot2
        const float Pp0 = half ? P3b : P[0];
        const float Pp1 = half ? P4b : P[1];
        const float F0  = half ? actl[3] : f0b;   // odd: f3 local
        const float F1  = half ? actl[4] : f1b;   // odd: f4 local
        cS[0] = fmaf(F0,  cS[0], Pp0);
        cS[1] = fmaf(F1,  cS[1], Pp1);
        cS[2] = fmaf(f2b, cS[2], P2b);
        const float d0 = 1.0f + fast_exp2(cS[0]); // c~-space: 1+e^{-2c}
        const float d1 = 1.0f + fast_exp2(cS[1]);
        const float d2 = 1.0f + fast_exp2(cS[2]);
        const float q  = fast_rcp(d0 * d1);
        const float r0 = q * d1, r1 = q * d0;
        const float r2 = fast_rcp(d2);
        const float t0 = fmaf(r0, 2.0f, -1.0f);   // tanh: even c0 / odd c3
        const float t1 = fmaf(r1, 2.0f, -1.0f);   //       even c1 / odd c4
        const float t2 = fmaf(r2, 2.0f, -1.0f);   //       c2 (both)
        const float o0b = dpp_q<0xF5>(acth[0]);   // o0 -> both
        const float o1b = dpp_q<0xF5>(acth[1]);
        const float o2b = dpp_q<0xF5>(acth[2]);   // uniform slot2
        const float O0 = half ? acth[3] : o0b;    // odd: o3 local
        const float O1 = half ? acth[4] : o1b;    // odd: o4 local
        const float hp0 = O0  * t0;               // even h0 / odd h3
        const float hp1 = O1  * t1;               // even h1 / odd h4
        const float hp2 = o2b * t2;               // h2 (both)
        H[0] = dpp_q<0xA0>(hp0);
        H[1] = dpp_q<0xA0>(hp1);
        H[2] = dpp_q<0xA0>(hp2);
        H[3] = dpp_q<0xF5>(hp0);
        H[4] = dpp_q<0xF5>(hp1);
    };

    const int rrow = lane >> 4;         // 0..3
    const int ccol = (lane & 15) << 2;  // 0,4,...,60

    for (int t0i = 0; t0i < T_; t0i += TTILE) {
        __syncthreads();
        // stage 32 rows x up-to-64 cols, coalesced float4 loads
#pragma unroll
        for (int it = 0; it < 8; ++it) {
            const int r = it * 4 + rrow;
            if (t0i + ccol < T_) {
                const float4 v = *(const float4*)(xblk + (size_t)r * T_ + (t0i + ccol));
                *(float4*)&xs[r * LDS_STRIDE + ccol] = v;
            }
        }
        __syncthreads();

        const int steps = min(TTILE, T_ - t0i); // 64 or 24
        const float* xr = &xs[s * LDS_STRIDE];
        for (int tt = 0; tt < steps; tt += 4) {
            const float4 xv4 = *(const float4*)&xr[tt];
            step(xv4.x);
            step(xv4.y);
            step(xv4.z);
            step(xv4.w);
        }
    }

    // ---- head: hid = H@fc_w.T + fc_b ; out = sigmoid(hid@out_w.T + out_b) ----
    if (half == 0) {
        float acc = out_b[0];
#pragma unroll
        for (int j = 0; j < 15; ++j) {
            float hid = fc_b[j];
#pragma unroll
            for (int k = 0; k < 5; ++k) hid = fmaf(H[k], fc_w[j * 5 + k], hid);
            acc = fmaf(hid, out_w[j], acc);
        }
        out[seq] = fast_rcp(1.0f + fast_exp2(-acc * LOG2E));
    }
}

extern "C" void kernel_launch(void* const* d_in, const int* in_sizes, int n_in,
                              void* d_out, int out_size, void* d_ws, size_t ws_size,
                              hipStream_t stream) {
    const float* x    = (const float*)d_in[0];
    const float* w_ih = (const float*)d_in[1];
    const float* w_hh = (const float*)d_in[2];
    const float* b_ih = (const float*)d_in[3];
    const float* b_hh = (const float*)d_in[4];
    const float* fc_w = (const float*)d_in[5];
    const float* fc_b = (const float*)d_in[6];
    const float* out_w = (const float*)d_in[7];
    const float* out_b = (const float*)d_in[8];
    float* out = (float*)d_out;

    const int N = in_sizes[0] / T_;             // 32768
    const int grid = N / SEQ_PER_BLOCK;         // 1024 blocks -> 1 wave/SIMD
    hipLaunchKernelGGL(lstm_kernel, dim3(grid), dim3(64), 0, stream,
                       x, w_ih, w_hh, b_ih, b_hh, fc_w, fc_b, out_w, out_b, out);
}

// Round 9
// 260.837 us; speedup vs baseline: 1.0756x; 1.0421x over previous
//
#include <hip/hip_runtime.h>
#include <math.h>

// LSTM: N=32768 seqs, T=600, H=5, input dim 1.
// 2 lanes/seq. R9 = R8 + unit-ownership rows + double-buffered x staging.
// Row assignment (per lane, 5 v2f pairs):
//   even: p0={i0,g0} p1={i1,g1} p2={i2,g2} p3={f0,o0} p4={f1,o1}
//   odd : p0={i3,g3} p1={i4,g4} p2={f2,o2} p3={f3,o3} p4={f4,o4}
// -> c-update for units 0,1 (even) / 3,4 (odd) is lane-LOCAL (no cndmask);
//    unit 2 shared via 3 DPP broadcasts; H redistributed with 4 DPPs (H2 free).
// g-rows pre-scaled -2log2e, others -log2e; g-activation emits
// g~ = -2log2e*tanh(g) so c is tracked in c~ = -2log2e*c space (exp2 direct).
// Block = 64 = 1 wave = 32 seqs; grid = 1024 -> 1 wave/SIMD chip-wide.

#define LOG2E 1.44269504088896340736f

typedef float v2f __attribute__((ext_vector_type(2)));

constexpr int T_ = 600;
constexpr int SEQ_PER_BLOCK = 32;
constexpr int TTILE = 64;
constexpr int NTILES = (T_ + TTILE - 1) / TTILE;   // 10
constexpr int LDS_STRIDE = 68;   // 68%32=4 -> 2-way bank aliasing only (free)
constexpr int XBUF = SEQ_PER_BLOCK * LDS_STRIDE;   // floats per buffer

__device__ __forceinline__ float fast_rcp(float v)  { return __builtin_amdgcn_rcpf(v); }
__device__ __forceinline__ float fast_exp2(float v) { return __builtin_amdgcn_exp2f(v); }

// quad_perm DPP: 0xA0 = [0,0,2,2] (even lane of pair -> both),
//                0xF5 = [1,1,3,3] (odd lane of pair -> both)
template <int CTRL>
__device__ __forceinline__ float dpp_q(float v) {
    const int x = __float_as_int(v);
    return __int_as_float(__builtin_amdgcn_update_dpp(x, x, CTRL, 0xF, 0xF, false));
}

__global__ __launch_bounds__(64, 1) void lstm_kernel(
    const float* __restrict__ x,
    const float* __restrict__ w_ih,   // (20,1)
    const float* __restrict__ w_hh,   // (20,5)
    const float* __restrict__ b_ih,   // (20,)
    const float* __restrict__ b_hh,   // (20,)
    const float* __restrict__ fc_w,   // (15,5)
    const float* __restrict__ fc_b,   // (15,)
    const float* __restrict__ out_w,  // (1,15)
    const float* __restrict__ out_b,  // (1,)
    float* __restrict__ out)          // (N,1)
{
    __shared__ float xs[2 * XBUF];

    const int lane = threadIdx.x;     // 0..63
    const int s    = lane >> 1;       // local sequence 0..31
    const int half = lane & 1;
    const int seq  = blockIdx.x * SEQ_PER_BLOCK + s;

    // ---- row tables (rows: i=0..4, f=5..9, g=10..14, o=15..19) ----
    const int rloT[2][5] = {{0, 1, 2, 5, 6}, {3, 4, 7, 8, 9}};
    const int rhiT[2][5] = {{10, 11, 12, 15, 16}, {13, 14, 17, 18, 19}};
    const int gtT [2][5] = {{1, 1, 1, 0, 0}, {1, 1, 0, 0, 0}};   // hi-elem is g(tanh)?

    v2f wih2[5], bb2[5], whh2[5][5], A2[5], B2[5];
#pragma unroll
    for (int p = 0; p < 5; ++p) {
        const int rlo = rloT[half][p], rhi = rhiT[half][p];
        const int gt  = gtT[half][p];
        const float sl = -LOG2E;
        const float sh = gt ? (-2.0f * LOG2E) : (-LOG2E);
        wih2[p] = (v2f){ w_ih[rlo] * sl, w_ih[rhi] * sh };
        bb2[p]  = (v2f){ (b_ih[rlo] + b_hh[rlo]) * sl,
                         (b_ih[rhi] + b_hh[rhi]) * sh };
#pragma unroll
        for (int k = 0; k < 5; ++k)
            whh2[p][k] = (v2f){ w_hh[rlo * 5 + k] * sl, w_hh[rhi * 5 + k] * sh };
        // hi transform: g -> -2L*tanh(g) = fma(sig, -4L, 2L); sigmoid -> identity
        A2[p] = (v2f){ 1.0f, gt ? (-4.0f * LOG2E) : 1.0f };
        B2[p] = (v2f){ 0.0f, gt ? ( 2.0f * LOG2E) : 0.0f };
    }

    float H[5] = {0.f, 0.f, 0.f, 0.f, 0.f};   // true h, uniform on both lanes
    float cA = 0.f, cB = 0.f, cC = 0.f;       // c~ slots: even(c0,c1,c2) odd(c3,c4,c2)

    const float* xblk = x + (size_t)(blockIdx.x * SEQ_PER_BLOCK) * T_;

    auto step = [&](float xt) {
        // ---- gate pre-activations (pre-scaled), packed ----
        const v2f x2 = (v2f){ xt, xt };
        v2f g2[5];
#pragma unroll
        for (int p = 0; p < 5; ++p) g2[p] = x2 * wih2[p] + bb2[p];
#pragma unroll
        for (int k = 0; k < 5; ++k) {
            const v2f h2 = (v2f){ H[k], H[k] };
#pragma unroll
            for (int p = 0; p < 5; ++p) g2[p] += h2 * whh2[p][k];
        }
        // ---- activations: r = rcp(1+exp2(g)) pairwise, then packed transform ----
        v2f act2[5];
#pragma unroll
        for (int p = 0; p < 5; ++p) {
            v2f d2;
            d2.x = 1.0f + fast_exp2(g2[p].x);
            d2.y = 1.0f + fast_exp2(g2[p].y);
            const float rp = fast_rcp(d2.x * d2.y);
            const v2f r2 = (v2f){ rp * d2.y, rp * d2.x };
            act2[p] = r2 * A2[p] + B2[p];
        }
        // ---- update: owned units local; unit 2 via 3 broadcasts ----
        const float PA = act2[0].x * act2[0].y;          // i*g~ : u0 (even) / u3 (odd)
        const float PB = act2[1].x * act2[1].y;          // u1 / u4
        const float P2 = dpp_q<0xA0>(act2[2].x * act2[2].y);  // i2*g~2 -> both
        const float f2 = dpp_q<0xF5>(act2[2].x);              // f2 -> both
        const float o2 = dpp_q<0xF5>(act2[2].y);              // o2 -> both
        cA = fmaf(act2[3].x, cA, PA);                    // f_own * c + i*g~
        cB = fmaf(act2[4].x, cB, PB);
        cC = fmaf(f2, cC, P2);
        const float dA = 1.0f + fast_exp2(cA);           // c~-space: 1+e^{-2c}
        const float dB = 1.0f + fast_exp2(cB);
        const float dC = 1.0f + fast_exp2(cC);
        const float q  = fast_rcp(dA * dB);
        const float tA = fmaf(q * dB, 2.0f, -1.0f);      // tanh(c): u0/u3
        const float tB = fmaf(q * dA, 2.0f, -1.0f);      // u1/u4
        const float tC = fmaf(fast_rcp(dC), 2.0f, -1.0f);// u2 (both)
        const float hA = act2[3].y * tA;                 // o_own * tanh
        const float hB = act2[4].y * tB;
        const float hC = o2 * tC;                        // uniform already
        H[0] = dpp_q<0xA0>(hA);
        H[1] = dpp_q<0xA0>(hB);
        H[2] = hC;
        H[3] = dpp_q<0xF5>(hA);
        H[4] = dpp_q<0xF5>(hB);
    };

    const int rrow = lane >> 4;         // 0..3
    const int ccol = (lane & 15) << 2;  // 0,4,...,60

    // ---- prologue: stage tile 0 ----
#pragma unroll
    for (int it = 0; it < 8; ++it) {
        const int r = it * 4 + rrow;
        const float4 v = *(const float4*)(xblk + (size_t)r * T_ + ccol);
        *(float4*)&xs[r * LDS_STRIDE + ccol] = v;
    }
    __syncthreads();

    for (int tile = 0; tile < NTILES; ++tile) {
        // ---- prefetch next tile into VGPRs (loads in flight during compute) ----
        float4 pf[8];
        const int tn  = tile + 1;
        const int t0n = tn * TTILE;
        if (tn < NTILES) {
#pragma unroll
            for (int it = 0; it < 8; ++it) {
                const int r = it * 4 + rrow;
                if (t0n + ccol < T_)
                    pf[it] = *(const float4*)(xblk + (size_t)r * T_ + (t0n + ccol));
            }
        }
        // ---- compute current tile ----
        const int t0i  = tile * TTILE;
        const int steps = min(TTILE, T_ - t0i);          // 64 or 24
        const float* xr = &xs[(tile & 1) * XBUF + s * LDS_STRIDE];
        for (int tt = 0; tt < steps; tt += 4) {
            const float4 xv4 = *(const float4*)&xr[tt];
            step(xv4.x);
            step(xv4.y);
            step(xv4.z);
            step(xv4.w);
        }
        // ---- stage prefetched tile into the other buffer ----
        if (tn < NTILES) {
#pragma unroll
            for (int it = 0; it < 8; ++it) {
                const int r = it * 4 + rrow;
                if (t0n + ccol < T_)
                    *(float4*)&xs[(tn & 1) * XBUF + r * LDS_STRIDE + ccol] = pf[it];
            }
            __syncthreads();
        }
    }

    // ---- head: hid = H@fc_w.T + fc_b ; out = sigmoid(hid@out_w.T + out_b) ----
    if (half == 0) {
        float acc = out_b[0];
#pragma unroll
        for (int j = 0; j < 15; ++j) {
            float hid = fc_b[j];
#pragma unroll
            for (int k = 0; k < 5; ++k) hid = fmaf(H[k], fc_w[j * 5 + k], hid);
            acc = fmaf(hid, out_w[j], acc);
        }
        out[seq] = fast_rcp(1.0f + fast_exp2(-acc * LOG2E));
    }
}

extern "C" void kernel_launch(void* const* d_in, const int* in_sizes, int n_in,
                              void* d_out, int out_size, void* d_ws, size_t ws_size,
                              hipStream_t stream) {
    const float* x    = (const float*)d_in[0];
    const float* w_ih = (const float*)d_in[1];
    const float* w_hh = (const float*)d_in[2];
    const float* b_ih = (const float*)d_in[3];
    const float* b_hh = (const float*)d_in[4];
    const float* fc_w = (const float*)d_in[5];
    const float* fc_b = (const float*)d_in[6];
    const float* out_w = (const float*)d_in[7];
    const float* out_b = (const float*)d_in[8];
    float* out = (float*)d_out;

    const int N = in_sizes[0] / T_;             // 32768
    const int grid = N / SEQ_PER_BLOCK;         // 1024 blocks -> 1 wave/SIMD
    hipLaunchKernelGGL(lstm_kernel, dim3(grid), dim3(64), 0, stream,
                       x, w_ih, w_hh, b_ih, b_hh, fc_w, fc_b, out_w, out_b, out);
}

// Round 10
// 258.277 us; speedup vs baseline: 1.0863x; 1.0099x over previous
//
#include <hip/hip_runtime.h>
#include <math.h>

// LSTM: N=32768 seqs, T=600, H=5, input dim 1.
// 2 lanes/seq. R10 = R9's unit-ownership step + R8's simple staging
// (R9's VGPR prefetch spilled to scratch: WRITE_SIZE 128KB->34MB — reverted).
// Row assignment (per lane, 5 v2f pairs):
//   even: p0={i0,g0} p1={i1,g1} p2={i2,g2} p3={f0,o0} p4={f1,o1}
//   odd : p0={i3,g3} p1={i4,g4} p2={f2,o2} p3={f3,o3} p4={f4,o4}
// -> c-update for units 0,1 (even) / 3,4 (odd) lane-local; unit 2 via 3 DPP
//    broadcasts; H redistributed with 4 DPPs (H2 uniform for free).
// g-rows pre-scaled -2log2e, others -log2e; g-activation emits
// g~ = -2log2e*tanh(g); c tracked in c~ = -2log2e*c space (exp2 direct).
// Activation transform applied scalar to g-elements only (sigmoid = identity).
// Block = 64 = 1 wave = 32 seqs; grid = 1024 -> 1 wave/SIMD chip-wide.

#define LOG2E 1.44269504088896340736f

typedef float v2f __attribute__((ext_vector_type(2)));

constexpr int T_ = 600;
constexpr int SEQ_PER_BLOCK = 32;
constexpr int TTILE = 64;
constexpr int LDS_STRIDE = 68;   // 68%32=4 -> 2-way bank aliasing only (free)

__device__ __forceinline__ float fast_rcp(float v)  { return __builtin_amdgcn_rcpf(v); }
__device__ __forceinline__ float fast_exp2(float v) { return __builtin_amdgcn_exp2f(v); }

// quad_perm DPP: 0xA0 = [0,0,2,2] (even lane of pair -> both),
//                0xF5 = [1,1,3,3] (odd lane of pair -> both)
template <int CTRL>
__device__ __forceinline__ float dpp_q(float v) {
    const int x = __float_as_int(v);
    return __int_as_float(__builtin_amdgcn_update_dpp(x, x, CTRL, 0xF, 0xF, false));
}

__global__ __launch_bounds__(64, 1) void lstm_kernel(
    const float* __restrict__ x,
    const float* __restrict__ w_ih,   // (20,1)
    const float* __restrict__ w_hh,   // (20,5)
    const float* __restrict__ b_ih,   // (20,)
    const float* __restrict__ b_hh,   // (20,)
    const float* __restrict__ fc_w,   // (15,5)
    const float* __restrict__ fc_b,   // (15,)
    const float* __restrict__ out_w,  // (1,15)
    const float* __restrict__ out_b,  // (1,)
    float* __restrict__ out)          // (N,1)
{
    __shared__ float xs[SEQ_PER_BLOCK * LDS_STRIDE];

    const int lane = threadIdx.x;     // 0..63
    const int s    = lane >> 1;       // local sequence 0..31
    const int half = lane & 1;
    const int seq  = blockIdx.x * SEQ_PER_BLOCK + s;

    // ---- row tables (rows: i=0..4, f=5..9, g=10..14, o=15..19) ----
    const int rloT[2][5] = {{0, 1, 2, 5, 6}, {3, 4, 7, 8, 9}};
    const int rhiT[2][5] = {{10, 11, 12, 15, 16}, {13, 14, 17, 18, 19}};
    const int gtT [2][5] = {{1, 1, 1, 0, 0}, {1, 1, 0, 0, 0}};   // hi-elem is g(tanh)?

    v2f wih2[5], bb2[5], whh2[5][5];
#pragma unroll
    for (int p = 0; p < 5; ++p) {
        const int rlo = rloT[half][p], rhi = rhiT[half][p];
        const float sl = -LOG2E;
        const float sh = gtT[half][p] ? (-2.0f * LOG2E) : (-LOG2E);
        wih2[p] = (v2f){ w_ih[rlo] * sl, w_ih[rhi] * sh };
        bb2[p]  = (v2f){ (b_ih[rlo] + b_hh[rlo]) * sl,
                         (b_ih[rhi] + b_hh[rhi]) * sh };
#pragma unroll
        for (int k = 0; k < 5; ++k)
            whh2[p][k] = (v2f){ w_hh[rlo * 5 + k] * sl, w_hh[rhi * 5 + k] * sh };
    }
    // number of leading pairs whose hi element is a g-row (needs tanh transform)
    const int ng = half ? 2 : 3;

    float H[5] = {0.f, 0.f, 0.f, 0.f, 0.f};   // true h, uniform on both lanes
    float cA = 0.f, cB = 0.f, cC = 0.f;       // c~ slots: even(c0,c1,c2) odd(c3,c4,c2)

    const float* xblk = x + (size_t)(blockIdx.x * SEQ_PER_BLOCK) * T_;

    auto step = [&](float xt) {
        // ---- gate pre-activations (pre-scaled), packed ----
        const v2f x2 = (v2f){ xt, xt };
        v2f g2[5];
#pragma unroll
        for (int p = 0; p < 5; ++p) g2[p] = x2 * wih2[p] + bb2[p];
#pragma unroll
        for (int k = 0; k < 5; ++k) {
            const v2f h2 = (v2f){ H[k], H[k] };
#pragma unroll
            for (int p = 0; p < 5; ++p) g2[p] += h2 * whh2[p][k];
        }
        // ---- activations: r = rcp(1+exp2(g)) pairwise ----
        v2f act2[5];
#pragma unroll
        for (int p = 0; p < 5; ++p) {
            const float dx = 1.0f + fast_exp2(g2[p].x);
            const float dy = 1.0f + fast_exp2(g2[p].y);
            const float rp = fast_rcp(dx * dy);
            act2[p].x = rp * dy;
            act2[p].y = rp * dx;
        }
        // g-elements only: g~ = -2log2e*tanh(g) = fma(sig, -4L, 2L)
#pragma unroll
        for (int p = 0; p < 3; ++p)
            if (p < ng)
                act2[p].y = fmaf(act2[p].y, -4.0f * LOG2E, 2.0f * LOG2E);
        // ---- update: owned units local; unit 2 via 3 broadcasts ----
        const float PA = act2[0].x * act2[0].y;               // i*g~ : u0 / u3
        const float PB = act2[1].x * act2[1].y;               // u1 / u4
        const float P2 = dpp_q<0xA0>(act2[2].x * act2[2].y);  // i2*g~2 -> both
        const float f2 = dpp_q<0xF5>(act2[2].x);              // f2 -> both
        const float o2 = dpp_q<0xF5>(act2[2].y);              // o2 -> both
        cA = fmaf(act2[3].x, cA, PA);                         // f_own*c + i*g~
        cB = fmaf(act2[4].x, cB, PB);
        cC = fmaf(f2, cC, P2);
        const float dA = 1.0f + fast_exp2(cA);                // c~-space: 1+e^{-2c}
        const float dB = 1.0f + fast_exp2(cB);
        const float dC = 1.0f + fast_exp2(cC);
        const float q  = fast_rcp(dA * dB);
        const float tA = fmaf(q * dB, 2.0f, -1.0f);           // tanh(c): u0/u3
        const float tB = fmaf(q * dA, 2.0f, -1.0f);           // u1/u4
        const float tC = fmaf(fast_rcp(dC), 2.0f, -1.0f);     // u2 (both)
        const float hA = act2[3].y * tA;                      // o_own * tanh
        const float hB = act2[4].y * tB;
        H[0] = dpp_q<0xA0>(hA);
        H[1] = dpp_q<0xA0>(hB);
        H[2] = o2 * tC;                                       // uniform already
        H[3] = dpp_q<0xF5>(hA);
        H[4] = dpp_q<0xF5>(hB);
    };

    const int rrow = lane >> 4;         // 0..3
    const int ccol = (lane & 15) << 2;  // 0,4,...,60

    for (int t0i = 0; t0i < T_; t0i += TTILE) {
        __syncthreads();
        // stage 32 rows x up-to-64 cols, coalesced float4 loads
#pragma unroll
        for (int it = 0; it < 8; ++it) {
            const int r = it * 4 + rrow;
            if (t0i + ccol < T_) {
                const float4 v = *(const float4*)(xblk + (size_t)r * T_ + (t0i + ccol));
                *(float4*)&xs[r * LDS_STRIDE + ccol] = v;
            }
        }
        __syncthreads();

        const int steps = min(TTILE, T_ - t0i);   // 64 or 24
        const float* xr = &xs[s * LDS_STRIDE];
        for (int tt = 0; tt < steps; tt += 4) {
            const float4 xv4 = *(const float4*)&xr[tt];
            step(xv4.x);
            step(xv4.y);
            step(xv4.z);
            step(xv4.w);
        }
    }

    // ---- head: hid = H@fc_w.T + fc_b ; out = sigmoid(hid@out_w.T + out_b) ----
    if (half == 0) {
        float acc = out_b[0];
#pragma unroll
        for (int j = 0; j < 15; ++j) {
            float hid = fc_b[j];
#pragma unroll
            for (int k = 0; k < 5; ++k) hid = fmaf(H[k], fc_w[j * 5 + k], hid);
            acc = fmaf(hid, out_w[j], acc);
        }
        out[seq] = fast_rcp(1.0f + fast_exp2(-acc * LOG2E));
    }
}

extern "C" void kernel_launch(void* const* d_in, const int* in_sizes, int n_in,
                              void* d_out, int out_size, void* d_ws, size_t ws_size,
                              hipStream_t stream) {
    const float* x    = (const float*)d_in[0];
    const float* w_ih = (const float*)d_in[1];
    const float* w_hh = (const float*)d_in[2];
    const float* b_ih = (const float*)d_in[3];
    const float* b_hh = (const float*)d_in[4];
    const float* fc_w = (const float*)d_in[5];
    const float* fc_b = (const float*)d_in[6];
    const float* out_w = (const float*)d_in[7];
    const float* out_b = (const float*)d_in[8];
    float* out = (float*)d_out;

    const int N = in_sizes[0] / T_;             // 32768
    const int grid = N / SEQ_PER_BLOCK;         // 1024 blocks -> 1 wave/SIMD
    hipLaunchKernelGGL(lstm_kernel, dim3(grid), dim3(64), 0, stream,
                       x, w_ih, w_hh, b_ih, b_hh, fc_w, fc_b, out_w, out_b, out);
}

// Round 11
// 248.041 us; speedup vs baseline: 1.1311x; 1.0413x over previous
//
#include <hip/hip_runtime.h>
#include <math.h>

// LSTM: N=32768 seqs, T=600, H=5, input dim 1.
// 2 lanes/seq. R11 = R10 + latency hiding on the stall side (busy side is
// near the trans-issue floor: ~20 trans/step ~= 320 of 499 busy cyc/step):
//  - LDS read prefetch: next float4 loaded 4 steps before use (was: ~120cyc
//    lgkm latency exposed every 4 steps ~= 30 cyc/step)
//  - global->VGPR tile prefetch issued right after barrier, UNCONDITIONAL
//    with clamped tile/col (R9's spill came from conditionally-defined pf[];
//    WRITE_SIZE is the spill canary), ds_write after compute, dbuf LDS.
// Row assignment (per lane, 5 v2f pairs):
//   even: p0={i0,g0} p1={i1,g1} p2={i2,g2} p3={f0,o0} p4={f1,o1}
//   odd : p0={i3,g3} p1={i4,g4} p2={f2,o2} p3={f3,o3} p4={f4,o4}
// c-update units 0,1 (even) / 3,4 (odd) lane-local; unit 2 via 3 DPP
// broadcasts; H redistributed with 4 DPPs. g-rows pre-scaled -2log2e, others
// -log2e; g-activation emits g~ = -2log2e*tanh(g); c tracked in c~ space.
// Block = 64 = 1 wave = 32 seqs; grid = 1024 -> 1 wave/SIMD chip-wide.

#define LOG2E 1.44269504088896340736f

typedef float v2f __attribute__((ext_vector_type(2)));

constexpr int T_ = 600;
constexpr int SEQ_PER_BLOCK = 32;
constexpr int TTILE = 64;
constexpr int NTILES = (T_ + TTILE - 1) / TTILE;   // 10 (last tile: 24 steps)
constexpr int LDS_STRIDE = 68;   // 16B-aligned rows; 4-way bank alias on b128 (minor)
constexpr int XBUF = SEQ_PER_BLOCK * LDS_STRIDE;

__device__ __forceinline__ float fast_rcp(float v)  { return __builtin_amdgcn_rcpf(v); }
__device__ __forceinline__ float fast_exp2(float v) { return __builtin_amdgcn_exp2f(v); }

// quad_perm DPP: 0xA0 = [0,0,2,2] (even lane of pair -> both),
//                0xF5 = [1,1,3,3] (odd lane of pair -> both)
template <int CTRL>
__device__ __forceinline__ float dpp_q(float v) {
    const int x = __float_as_int(v);
    return __int_as_float(__builtin_amdgcn_update_dpp(x, x, CTRL, 0xF, 0xF, false));
}

__global__ __launch_bounds__(64, 1) void lstm_kernel(
    const float* __restrict__ x,
    const float* __restrict__ w_ih,   // (20,1)
    const float* __restrict__ w_hh,   // (20,5)
    const float* __restrict__ b_ih,   // (20,)
    const float* __restrict__ b_hh,   // (20,)
    const float* __restrict__ fc_w,   // (15,5)
    const float* __restrict__ fc_b,   // (15,)
    const float* __restrict__ out_w,  // (1,15)
    const float* __restrict__ out_b,  // (1,)
    float* __restrict__ out)          // (N,1)
{
    __shared__ float xs[2 * XBUF];

    const int lane = threadIdx.x;     // 0..63
    const int s    = lane >> 1;       // local sequence 0..31
    const int half = lane & 1;
    const int seq  = blockIdx.x * SEQ_PER_BLOCK + s;

    // ---- row tables (rows: i=0..4, f=5..9, g=10..14, o=15..19) ----
    const int rloT[2][5] = {{0, 1, 2, 5, 6}, {3, 4, 7, 8, 9}};
    const int rhiT[2][5] = {{10, 11, 12, 15, 16}, {13, 14, 17, 18, 19}};
    const int gtT [2][5] = {{1, 1, 1, 0, 0}, {1, 1, 0, 0, 0}};   // hi-elem is g(tanh)?

    v2f wih2[5], bb2[5], whh2[5][5];
#pragma unroll
    for (int p = 0; p < 5; ++p) {
        const int rlo = rloT[half][p], rhi = rhiT[half][p];
        const float sl = -LOG2E;
        const float sh = gtT[half][p] ? (-2.0f * LOG2E) : (-LOG2E);
        wih2[p] = (v2f){ w_ih[rlo] * sl, w_ih[rhi] * sh };
        bb2[p]  = (v2f){ (b_ih[rlo] + b_hh[rlo]) * sl,
                         (b_ih[rhi] + b_hh[rhi]) * sh };
#pragma unroll
        for (int k = 0; k < 5; ++k)
            whh2[p][k] = (v2f){ w_hh[rlo * 5 + k] * sl, w_hh[rhi * 5 + k] * sh };
    }
    const int ng = half ? 2 : 3;   // leading pairs whose hi element is a g-row

    float H[5] = {0.f, 0.f, 0.f, 0.f, 0.f};   // true h, uniform on both lanes
    float cA = 0.f, cB = 0.f, cC = 0.f;       // c~ slots: even(c0,c1,c2) odd(c3,c4,c2)

    const float* xblk = x + (size_t)(blockIdx.x * SEQ_PER_BLOCK) * T_;

    auto step = [&](float xt) {
        const v2f x2 = (v2f){ xt, xt };
        v2f g2[5];
#pragma unroll
        for (int p = 0; p < 5; ++p) g2[p] = x2 * wih2[p] + bb2[p];
#pragma unroll
        for (int k = 0; k < 5; ++k) {
            const v2f h2 = (v2f){ H[k], H[k] };
#pragma unroll
            for (int p = 0; p < 5; ++p) g2[p] += h2 * whh2[p][k];
        }
        v2f act2[5];
#pragma unroll
        for (int p = 0; p < 5; ++p) {
            const float dx = 1.0f + fast_exp2(g2[p].x);
            const float dy = 1.0f + fast_exp2(g2[p].y);
            const float rp = fast_rcp(dx * dy);
            act2[p].x = rp * dy;
            act2[p].y = rp * dx;
        }
#pragma unroll
        for (int p = 0; p < 3; ++p)
            if (p < ng)
                act2[p].y = fmaf(act2[p].y, -4.0f * LOG2E, 2.0f * LOG2E);
        const float PA = act2[0].x * act2[0].y;               // i*g~ : u0 / u3
        const float PB = act2[1].x * act2[1].y;               // u1 / u4
        const float P2 = dpp_q<0xA0>(act2[2].x * act2[2].y);  // i2*g~2 -> both
        const float f2 = dpp_q<0xF5>(act2[2].x);              // f2 -> both
        const float o2 = dpp_q<0xF5>(act2[2].y);              // o2 -> both
        cA = fmaf(act2[3].x, cA, PA);
        cB = fmaf(act2[4].x, cB, PB);
        cC = fmaf(f2, cC, P2);
        const float dA = 1.0f + fast_exp2(cA);
        const float dB = 1.0f + fast_exp2(cB);
        const float dC = 1.0f + fast_exp2(cC);
        const float q  = fast_rcp(dA * dB);
        const float tA = fmaf(q * dB, 2.0f, -1.0f);
        const float tB = fmaf(q * dA, 2.0f, -1.0f);
        const float tC = fmaf(fast_rcp(dC), 2.0f, -1.0f);
        const float hA = act2[3].y * tA;
        const float hB = act2[4].y * tB;
        H[0] = dpp_q<0xA0>(hA);
        H[1] = dpp_q<0xA0>(hB);
        H[2] = o2 * tC;
        H[3] = dpp_q<0xF5>(hA);
        H[4] = dpp_q<0xF5>(hB);
    };

    const int rrow = lane >> 4;         // 0..3
    const int ccol = (lane & 15) << 2;  // 0,4,...,60

    // ---- prologue: stage tile 0 into buffer 0 ----
#pragma unroll
    for (int it = 0; it < 8; ++it) {
        const int r = it * 4 + rrow;
        const float4 v = *(const float4*)(xblk + (size_t)r * T_ + ccol);
        *(float4*)&xs[r * LDS_STRIDE + ccol] = v;
    }
    __syncthreads();

    for (int tile = 0; tile < NTILES; ++tile) {
        // ---- issue next-tile global loads NOW (unconditional, clamped) ----
        const int tpf  = (tile + 1 < NTILES) ? (tile + 1) : (NTILES - 1);
        const int cpf  = (tpf * TTILE + ccol <= T_ - 4) ? (tpf * TTILE + ccol) : (T_ - 4);
        float4 pf[8];
#pragma unroll
        for (int it = 0; it < 8; ++it) {
            const int r = it * 4 + rrow;
            pf[it] = *(const float4*)(xblk + (size_t)r * T_ + cpf);
        }
        // ---- compute current tile, LDS reads prefetched 4 steps ahead ----
        const int t0i   = tile * TTILE;
        const int steps = (T_ - t0i >= TTILE) ? TTILE : (T_ - t0i);   // 64 or 24
        const float* xr = &xs[(tile & 1) * XBUF + s * LDS_STRIDE];
        float4 cur = *(const float4*)&xr[0];
        for (int tt = 0; tt < steps; tt += 4) {
            const float4 nxt = *(const float4*)&xr[tt + 4];  // pad/garbage at edge, unused
            step(cur.x);
            step(cur.y);
            step(cur.z);
            step(cur.w);
            cur = nxt;
        }
        // ---- stage prefetched tile into the other buffer (unconditional) ----
        float* xw = &xs[((tile + 1) & 1) * XBUF];
#pragma unroll
        for (int it = 0; it < 8; ++it) {
            const int r = it * 4 + rrow;
            *(float4*)&xw[r * LDS_STRIDE + ccol] = pf[it];
        }
        __syncthreads();
    }

    // ---- head: hid = H@fc_w.T + fc_b ; out = sigmoid(hid@out_w.T + out_b) ----
    if (half == 0) {
        float acc = out_b[0];
#pragma unroll
        for (int j = 0; j < 15; ++j) {
            float hid = fc_b[j];
#pragma unroll
            for (int k = 0; k < 5; ++k) hid = fmaf(H[k], fc_w[j * 5 + k], hid);
            acc = fmaf(hid, out_w[j], acc);
        }
        out[seq] = fast_rcp(1.0f + fast_exp2(-acc * LOG2E));
    }
}

extern "C" void kernel_launch(void* const* d_in, const int* in_sizes, int n_in,
                              void* d_out, int out_size, void* d_ws, size_t ws_size,
                              hipStream_t stream) {
    const float* x    = (const float*)d_in[0];
    const float* w_ih = (const float*)d_in[1];
    const float* w_hh = (const float*)d_in[2];
    const float* b_ih = (const float*)d_in[3];
    const float* b_hh = (const float*)d_in[4];
    const float* fc_w = (const float*)d_in[5];
    const float* fc_b = (const float*)d_in[6];
    const float* out_w = (const float*)d_in[7];
    const float* out_b = (const float*)d_in[8];
    float* out = (float*)d_out;

    const int N = in_sizes[0] / T_;             // 32768
    const int grid = N / SEQ_PER_BLOCK;         // 1024 blocks -> 1 wave/SIMD
    hipLaunchKernelGGL(lstm_kernel, dim3(grid), dim3(64), 0, stream,
                       x, w_ih, w_hh, b_ih, b_hh, fc_w, fc_b, out_w, out_b, out);
}